// Round 6
// baseline (774.188 us; speedup 1.0000x reference)
//
#include <hip/hip_runtime.h>

#define T_STEPS 1024
#define BATCH 2048
#define BTILE 8
#define HS 36   // LDS row stride in u32 words; 36 % 32 == 4 -> conflict-free b128 reads

typedef short short8 __attribute__((ext_vector_type(8)));
typedef float f32x4 __attribute__((ext_vector_type(4)));

__device__ __forceinline__ float fast_rcp(float x) {
#if __has_builtin(__builtin_amdgcn_rcpf)
    return __builtin_amdgcn_rcpf(x);
#else
    return 1.0f / x;
#endif
}

__device__ __forceinline__ float fast_exp2(float x) {
#if __has_builtin(__builtin_amdgcn_exp2f)
    return __builtin_amdgcn_exp2f(x);
#else
    return exp2f(x);
#endif
}

__device__ __forceinline__ float sigf(float x) {
    return fast_rcp(1.0f + fast_exp2(-1.44269504f * x));
}

__device__ __forceinline__ float tanh_fast(float x) {
    float e = fast_exp2(2.88539008f * x);
    return 1.0f - 2.0f * fast_rcp(e + 1.0f);
}

// float -> bf16 bits (round-to-nearest-even)
__device__ __forceinline__ unsigned f2bf(float x) {
    unsigned u = __float_as_uint(x);
    unsigned r = u + 0x7FFFu + ((u >> 16) & 1u);
    return r >> 16;
}
__device__ __forceinline__ float bf2f(unsigned b) {
    return __uint_as_float(b << 16);
}

// DPP conventions (HW-validated R2-R5): 0x110+N: lane l <- lane l-N (in row-16);
// 0x100+N: lane l <- lane l+N. bank_mask: banks NOT selected keep OLD value.
// Gate redistribution, cell A: lane l (r=(l>>2)&3) wants reg r from lane l-4r.
__device__ __forceinline__ float sel4A(f32x4 a) {
    int v = __float_as_int(a[0]);                                        // bank 0 (r=0)
    v = __builtin_amdgcn_update_dpp(v, __float_as_int(a[1]), 0x114, 0xf, 0x2, false);
    v = __builtin_amdgcn_update_dpp(v, __float_as_int(a[2]), 0x118, 0xf, 0x4, false);
    v = __builtin_amdgcn_update_dpp(v, __float_as_int(a[3]), 0x11C, 0xf, 0x8, false);
    return __int_as_float(v);
}
// cell B (batch col +4): lane l wants reg r from lane l-4(r-1)
__device__ __forceinline__ float sel4B(f32x4 a) {
    int v = __float_as_int(a[1]);                                        // bank 1 (r=1)
    v = __builtin_amdgcn_update_dpp(v, __float_as_int(a[0]), 0x104, 0xf, 0x1, false);
    v = __builtin_amdgcn_update_dpp(v, __float_as_int(a[2]), 0x114, 0xf, 0x4, false);
    v = __builtin_amdgcn_update_dpp(v, __float_as_int(a[3]), 0x118, 0xf, 0x8, false);
    return __int_as_float(v);
}
__device__ __forceinline__ unsigned dpp_shl4u(unsigned v) {
    return (unsigned)__builtin_amdgcn_update_dpp(0, (int)v, 0x104, 0xf, 0xf, true);
}

// R5 structure widened to BTILE=8: MFMA cols 0..7 = 8 batches, each lane
// activates 2 cells (batches l&3 and 4+(l&3), same unit -> shared constants).
// 256 blocks = 1/CU, 1 wave/SIMD; latency hidden by intra-wave ILP.
__global__ __launch_bounds__(256, 1)
void lstm_v6_kernel(const float* __restrict__ input,
                    const float* __restrict__ W_ih0,
                    const float* __restrict__ W_hh0,
                    const float* __restrict__ b_ih0,
                    const float* __restrict__ b_hh0,
                    const float* __restrict__ W_ih1,
                    const float* __restrict__ W_hh1,
                    const float* __restrict__ b_ih1,
                    const float* __restrict__ b_hh1,
                    float* __restrict__ out)
{
    const int tid = threadIdx.x;
    const int w   = tid >> 6;
    const int l   = tid & 63;
    const int q16 = l >> 4;
    const int n16 = l & 15;
    const int nbA = l & 3;
    const int nbB = 4 + nbA;
    const int r   = (l >> 2) & 3;
    const int u   = 16 * w + 4 * q16 + r;
    const int bbase = blockIdx.x * BTILE;

    // [parity][h | c0hi | c0lo][batch-row][word]; rows 8..15 stay zero
    __shared__ __align__(16) unsigned Hbuf[2][3][16][HS];   // 13.8 KB
    __shared__ float Xb[2][BTILE][65];                      // 4.2 KB
    __shared__ float Lst[16];                               // h1[0..7], c1[8..15]

    for (int i = tid; i < 2 * 3 * 16 * HS; i += 256)
        reinterpret_cast<unsigned*>(Hbuf)[i] = 0u;
    if (tid < 16) Lst[tid] = 0.0f;

    // ---- L1 A-fragments: a1[g][kt] = W_hh0 tile (w+4g, kt) ----
    short8 a1[4][2];
    #pragma unroll
    for (int g = 0; g < 4; ++g) {
        #pragma unroll
        for (int kt = 0; kt < 2; ++kt) {
            const float* p = W_hh0 + (size_t)(16 * (w + 4 * g) + n16) * 64 + kt * 32 + q16 * 8;
            short8 a;
            #pragma unroll
            for (int j = 0; j < 8; ++j) a[j] = (short)f2bf(p[j]);
            a1[g][kt] = a;
        }
    }
    // ---- L2 A-fragments (hi/lo split), rows m>=4 zero ----
    short8 a2h[2], a2l[2];
    #pragma unroll
    for (int kt = 0; kt < 2; ++kt) {
        short8 ah = {0,0,0,0,0,0,0,0}, al = {0,0,0,0,0,0,0,0};
        if (n16 < 4) {
            const float* p = W_ih1 + (size_t)n16 * 64 + kt * 32 + q16 * 8;
            #pragma unroll
            for (int j = 0; j < 8; ++j) {
                unsigned hb = f2bf(p[j]);
                ah[j] = (short)hb;
                al[j] = (short)f2bf(p[j] - bf2f(hb));
            }
        }
        a2h[kt] = ah; a2l[kt] = al;
    }

    // activation constants for unit u (shared by both cells of this lane)
    float wg[4], bg[4];
    #pragma unroll
    for (int g = 0; g < 4; ++g) {
        int row = g * 64 + u;
        wg[g] = W_ih0[row];
        bg[g] = b_ih0[row] + b_hh0[row];
    }
    float whh1v[4], b1v[4];
    #pragma unroll
    for (int g = 0; g < 4; ++g) { whh1v[g] = W_hh1[g]; b1v[g] = b_ih1[g] + b_hh1[g]; }

    const float* inrowA = input + (size_t)(bbase + w) * T_STEPS;
    const float* inrowB = input + (size_t)(bbase + 4 + w) * T_STEPS;
    Xb[0][w][l]     = inrowA[l];
    Xb[0][4 + w][l] = inrowB[l];
    float xnA = 0.0f, xnB = 0.0f;
    float c0A = 0.0f, c0B = 0.0f;

    __syncthreads();

    int par = 0;
    #pragma unroll 2
    for (int t = 0; t < T_STEPS; ++t) {
        if ((t & 63) == 0 && t + 64 < T_STEPS) {
            xnA = inrowA[t + 64 + l];
            xnB = inrowB[t + 64 + l];
        }
        const int cp = (t >> 6) & 1;

        // ---- B-fragments: h(t-1), batches in cols 0..7 ----
        const unsigned* Hrow = &Hbuf[par][0][n16][0];
        short8 hb0 = *reinterpret_cast<const short8*>(Hrow + 4 * q16);
        short8 hb1 = *reinterpret_cast<const short8*>(Hrow + 16 + 4 * q16);

        // ---- L1 MFMA: acc[g] = gate-g rows, units 16w..16w+15, 8 batches ----
        f32x4 accv[4];
        #pragma unroll
        for (int g = 0; g < 4; ++g) {
            f32x4 z = {0.0f, 0.0f, 0.0f, 0.0f};
            z = __builtin_amdgcn_mfma_f32_16x16x32_bf16(a1[g][0], hb0, z, 0, 0, 0);
            z = __builtin_amdgcn_mfma_f32_16x16x32_bf16(a1[g][1], hb1, z, 0, 0, 0);
            accv[g] = z;
        }

        // ---- layer-2 for step t-1 (round-robin wave), in the MFMA shadow ----
        if (t > 0 && w == ((t - 1) & 3)) {
            const unsigned* Ch = &Hbuf[par][1][n16][0];
            const unsigned* Cl = &Hbuf[par][2][n16][0];
            short8 ch0 = *reinterpret_cast<const short8*>(Ch + 4 * q16);
            short8 ch1 = *reinterpret_cast<const short8*>(Ch + 16 + 4 * q16);
            short8 cl0 = *reinterpret_cast<const short8*>(Cl + 4 * q16);
            short8 cl1 = *reinterpret_cast<const short8*>(Cl + 16 + 4 * q16);
            float h1p = Lst[n16 & 7];
            float c1p = Lst[8 + (n16 & 7)];
            f32x4 z = {0.0f, 0.0f, 0.0f, 0.0f};
            z = __builtin_amdgcn_mfma_f32_16x16x32_bf16(a2h[0], ch0, z, 0, 0, 0);
            z = __builtin_amdgcn_mfma_f32_16x16x32_bf16(a2h[1], ch1, z, 0, 0, 0);
            z = __builtin_amdgcn_mfma_f32_16x16x32_bf16(a2l[0], ch0, z, 0, 0, 0);
            z = __builtin_amdgcn_mfma_f32_16x16x32_bf16(a2l[1], ch1, z, 0, 0, 0);
            z = __builtin_amdgcn_mfma_f32_16x16x32_bf16(a2h[0], cl0, z, 0, 0, 0);
            z = __builtin_amdgcn_mfma_f32_16x16x32_bf16(a2h[1], cl1, z, 0, 0, 0);
            // valid rows g=reg at quad 0; cols 0..7 = batches
            float g1i = z[0] + b1v[0] + h1p * whh1v[0];
            float g1f = z[1] + b1v[1] + h1p * whh1v[1];
            float g1g = z[2] + b1v[2] + h1p * whh1v[2];
            float g1o = z[3] + b1v[3] + h1p * whh1v[3];
            float c1n = sigf(g1f) * c1p + sigf(g1i) * tanh_fast(g1g);
            float h1n = sigf(g1o) * tanh_fast(c1n);
            if (l < 8) {
                out[(size_t)(bbase + l) * T_STEPS + (t - 1)] = c1n;
                Lst[l] = h1n;
                Lst[8 + l] = c1n;
            }
        }

        // ---- in-register gate redistribution (bank-masked DPP) ----
        float g4A[4], g4B[4];
        #pragma unroll
        for (int g = 0; g < 4; ++g) {
            g4A[g] = sel4A(accv[g]);
            g4B[g] = sel4B(accv[g]);
        }

        // ---- activation: cell A (nbA, u) and cell B (nbB, u) ----
        float xA = Xb[cp][nbA][t & 63];
        float xB = Xb[cp][nbB][t & 63];

        float giA = g4A[0] + fmaf(xA, wg[0], bg[0]);
        float gfA = g4A[1] + fmaf(xA, wg[1], bg[1]);
        float ggA = g4A[2] + fmaf(xA, wg[2], bg[2]);
        float goA = g4A[3] + fmaf(xA, wg[3], bg[3]);
        float giB = g4B[0] + fmaf(xB, wg[0], bg[0]);
        float gfB = g4B[1] + fmaf(xB, wg[1], bg[1]);
        float ggB = g4B[2] + fmaf(xB, wg[2], bg[2]);
        float goB = g4B[3] + fmaf(xB, wg[3], bg[3]);

        float c0nA = sigf(gfA) * c0A + sigf(giA) * tanh_fast(ggA);
        float c0nB = sigf(gfB) * c0B + sigf(giB) * tanh_fast(ggB);
        c0A = c0nA;
        c0B = c0nB;
        float h0nA = sigf(goA) * tanh_fast(c0nA);
        float h0nB = sigf(goB) * tanh_fast(c0nB);

        // ---- pack h / c0hi / c0lo pairs; even-r lanes write pairs (u, u+1) ----
        unsigned hA  = f2bf(h0nA);
        unsigned cAh = f2bf(c0nA);
        unsigned cAl = f2bf(c0nA - bf2f(cAh));
        unsigned hB  = f2bf(h0nB);
        unsigned cBh = f2bf(c0nB);
        unsigned cBl = f2bf(c0nB - bf2f(cBh));
        unsigned hAp  = dpp_shl4u(hA);
        unsigned cAhp = dpp_shl4u(cAh);
        unsigned cAlp = dpp_shl4u(cAl);
        unsigned hBp  = dpp_shl4u(hB);
        unsigned cBhp = dpp_shl4u(cBh);
        unsigned cBlp = dpp_shl4u(cBl);
        if (!(l & 4)) {
            int widx = 8 * w + 2 * q16 + (r >> 1);
            Hbuf[par ^ 1][0][nbA][widx] = hA  | (hAp  << 16);
            Hbuf[par ^ 1][1][nbA][widx] = cAh | (cAhp << 16);
            Hbuf[par ^ 1][2][nbA][widx] = cAl | (cAlp << 16);
            Hbuf[par ^ 1][0][nbB][widx] = hB  | (hBp  << 16);
            Hbuf[par ^ 1][1][nbB][widx] = cBh | (cBhp << 16);
            Hbuf[par ^ 1][2][nbB][widx] = cBl | (cBlp << 16);
        }
        if ((t & 63) == 63 && t + 1 < T_STEPS) {
            Xb[cp ^ 1][w][l]     = xnA;
            Xb[cp ^ 1][4 + w][l] = xnB;
        }

        __syncthreads();
        par ^= 1;
    }

    // ---- epilogue: layer-2 for step 1023 (wave 3) ----
    if (w == 3) {
        const unsigned* Ch = &Hbuf[par][1][n16][0];
        const unsigned* Cl = &Hbuf[par][2][n16][0];
        short8 ch0 = *reinterpret_cast<const short8*>(Ch + 4 * q16);
        short8 ch1 = *reinterpret_cast<const short8*>(Ch + 16 + 4 * q16);
        short8 cl0 = *reinterpret_cast<const short8*>(Cl + 4 * q16);
        short8 cl1 = *reinterpret_cast<const short8*>(Cl + 16 + 4 * q16);
        float h1p = Lst[n16 & 7];
        float c1p = Lst[8 + (n16 & 7)];
        f32x4 z = {0.0f, 0.0f, 0.0f, 0.0f};
        z = __builtin_amdgcn_mfma_f32_16x16x32_bf16(a2h[0], ch0, z, 0, 0, 0);
        z = __builtin_amdgcn_mfma_f32_16x16x32_bf16(a2h[1], ch1, z, 0, 0, 0);
        z = __builtin_amdgcn_mfma_f32_16x16x32_bf16(a2l[0], ch0, z, 0, 0, 0);
        z = __builtin_amdgcn_mfma_f32_16x16x32_bf16(a2l[1], ch1, z, 0, 0, 0);
        z = __builtin_amdgcn_mfma_f32_16x16x32_bf16(a2h[0], cl0, z, 0, 0, 0);
        z = __builtin_amdgcn_mfma_f32_16x16x32_bf16(a2h[1], cl1, z, 0, 0, 0);
        float g1i = z[0] + b1v[0] + h1p * whh1v[0];
        float g1f = z[1] + b1v[1] + h1p * whh1v[1];
        float g1g = z[2] + b1v[2] + h1p * whh1v[2];
        float g1o = z[3] + b1v[3] + h1p * whh1v[3];
        float c1n = sigf(g1f) * c1p + sigf(g1i) * tanh_fast(g1g);
        if (l < 8)
            out[(size_t)(bbase + l) * T_STEPS + (T_STEPS - 1)] = c1n;
    }
}

extern "C" void kernel_launch(void* const* d_in, const int* in_sizes, int n_in,
                              void* d_out, int out_size, void* d_ws, size_t ws_size,
                              hipStream_t stream) {
    const float* input = (const float*)d_in[0];
    const float* W_ih0 = (const float*)d_in[1];
    const float* W_hh0 = (const float*)d_in[2];
    const float* b_ih0 = (const float*)d_in[3];
    const float* b_hh0 = (const float*)d_in[4];
    const float* W_ih1 = (const float*)d_in[5];
    const float* W_hh1 = (const float*)d_in[6];
    const float* b_ih1 = (const float*)d_in[7];
    const float* b_hh1 = (const float*)d_in[8];
    float* out = (float*)d_out;

    dim3 grid(BATCH / BTILE);   // 256 blocks -> 1 block/CU
    dim3 block(256);
    lstm_v6_kernel<<<grid, block, 0, stream>>>(
        input, W_ih0, W_hh0, b_ih0, b_hh0, W_ih1, W_hh1, b_ih1, b_hh1, out);
}

// Round 7
// 606.129 us; speedup vs baseline: 1.2773x; 1.2773x over previous
//
#include <hip/hip_runtime.h>

#define T_STEPS 1024
#define BATCH 2048
#define BTILE 4
#define HS 36   // LDS row stride in u32 words; 36 % 32 == 4 -> conflict-free b128 reads

typedef short short8 __attribute__((ext_vector_type(8)));
typedef float f32x4 __attribute__((ext_vector_type(4)));
typedef float f32x2 __attribute__((ext_vector_type(2)));

__device__ __forceinline__ float fast_rcp(float x) {
#if __has_builtin(__builtin_amdgcn_rcpf)
    return __builtin_amdgcn_rcpf(x);
#else
    return 1.0f / x;
#endif
}

__device__ __forceinline__ float fast_exp2(float x) {
#if __has_builtin(__builtin_amdgcn_exp2f)
    return __builtin_amdgcn_exp2f(x);
#else
    return exp2f(x);
#endif
}

__device__ __forceinline__ float sigf(float x) {
    return fast_rcp(1.0f + fast_exp2(-1.44269504f * x));
}

// packed 2-lane sigmoid: pk_mul + 2 exp + pk_add + 2 rcp
__device__ __forceinline__ f32x2 sigf2(f32x2 v) {
    f32x2 t = v * (-1.44269504f);
    f32x2 e = {fast_exp2(t[0]), fast_exp2(t[1])};
    e = e + 1.0f;
    return f32x2{fast_rcp(e[0]), fast_rcp(e[1])};
}

__device__ __forceinline__ float tanh_fast(float x) {
    float e = fast_exp2(2.88539008f * x);
    return 1.0f - 2.0f * fast_rcp(e + 1.0f);
}

// float -> bf16 bits (round-to-nearest-even) — setup only
__device__ __forceinline__ unsigned f2bf(float x) {
    unsigned u = __float_as_uint(x);
    unsigned r = u + 0x7FFFu + ((u >> 16) & 1u);
    return r >> 16;
}
__device__ __forceinline__ float bf2f(unsigned b) {
    return __uint_as_float(b << 16);
}

// packed bf16 convert: dst = {hi16=bf16(b), lo16=bf16(a)}, RNE
__device__ __forceinline__ unsigned cvt_pk_bf16(float a, float b) {
    unsigned r;
    asm("v_cvt_pk_bf16_f32 %0, %1, %2" : "=v"(r) : "v"(a), "v"(b));
    return r;
}

// DPP conventions (HW-validated R2-R6): 0x110+N: lane l <- lane l-N (row-16);
// 0x100+N: lane l <- lane l+N. bank_mask: unselected banks keep OLD dst value.
// Gate redistribution: lane l (r=(l>>2)&3) takes acc reg r from lane l-4r.
__device__ __forceinline__ float sel4A(f32x4 a) {
    int v = __float_as_int(a[0]);                                        // bank 0 (r=0)
    v = __builtin_amdgcn_update_dpp(v, __float_as_int(a[1]), 0x114, 0xf, 0x2, false);
    v = __builtin_amdgcn_update_dpp(v, __float_as_int(a[2]), 0x118, 0xf, 0x4, false);
    v = __builtin_amdgcn_update_dpp(v, __float_as_int(a[3]), 0x11C, 0xf, 0x8, false);
    return __int_as_float(v);
}
__device__ __forceinline__ float dpp_shl4f(float v) {
    return __int_as_float(__builtin_amdgcn_update_dpp(0, __float_as_int(v), 0x104, 0xf, 0xf, true));
}

// R5 structure (4 waves / 4 batches / 512 blocks / 2 per CU) with leaner issue:
// bank-masked DPP gate redistribution (12 inst), v_cvt_pk_bf16_f32 packing,
// packed-f32 gate math, and the L2 MFMA accumulation split into 2 depth-3 chains.
__global__ __launch_bounds__(256, 2)
void lstm_v7_kernel(const float* __restrict__ input,
                    const float* __restrict__ W_ih0,
                    const float* __restrict__ W_hh0,
                    const float* __restrict__ b_ih0,
                    const float* __restrict__ b_hh0,
                    const float* __restrict__ W_ih1,
                    const float* __restrict__ W_hh1,
                    const float* __restrict__ b_ih1,
                    const float* __restrict__ b_hh1,
                    float* __restrict__ out)
{
    const int tid = threadIdx.x;
    const int w   = tid >> 6;
    const int l   = tid & 63;
    const int q16 = l >> 4;
    const int n16 = l & 15;
    const int nb  = l & 3;
    const int r   = (l >> 2) & 3;
    const int u   = 16 * w + 4 * q16 + r;
    const int bbase = blockIdx.x * BTILE;

    __shared__ __align__(16) unsigned Hbuf[2][3][16][HS];   // 13.8 KB
    __shared__ float Xb[2][BTILE][65];
    __shared__ float Lst[8];                                // h1[0..3], c1[4..7]

    for (int i = tid; i < 2 * 3 * 16 * HS; i += 256)
        reinterpret_cast<unsigned*>(Hbuf)[i] = 0u;
    if (tid < 8) Lst[tid] = 0.0f;

    // ---- L1 A-fragments: a1[g][kt] = W_hh0 tile (w+4g, kt) ----
    short8 a1[4][2];
    #pragma unroll
    for (int g = 0; g < 4; ++g) {
        #pragma unroll
        for (int kt = 0; kt < 2; ++kt) {
            const float* p = W_hh0 + (size_t)(16 * (w + 4 * g) + n16) * 64 + kt * 32 + q16 * 8;
            short8 a;
            #pragma unroll
            for (int j = 0; j < 8; ++j) a[j] = (short)f2bf(p[j]);
            a1[g][kt] = a;
        }
    }
    // ---- L2 A-fragments (hi/lo split), rows m>=4 zero ----
    short8 a2h[2], a2l[2];
    #pragma unroll
    for (int kt = 0; kt < 2; ++kt) {
        short8 ah = {0,0,0,0,0,0,0,0}, al = {0,0,0,0,0,0,0,0};
        if (n16 < 4) {
            const float* p = W_ih1 + (size_t)n16 * 64 + kt * 32 + q16 * 8;
            #pragma unroll
            for (int j = 0; j < 8; ++j) {
                unsigned hb = f2bf(p[j]);
                ah[j] = (short)hb;
                al[j] = (short)f2bf(p[j] - bf2f(hb));
            }
        }
        a2h[kt] = ah; a2l[kt] = al;
    }

    // activation constants for cell (nb, u), packed as float2 pairs
    f32x2 w01, w23, b01, b23;
    {
        float wgv[4], bgv[4];
        #pragma unroll
        for (int g = 0; g < 4; ++g) {
            int row = g * 64 + u;
            wgv[g] = W_ih0[row];
            bgv[g] = b_ih0[row] + b_hh0[row];
        }
        w01 = f32x2{wgv[0], wgv[1]}; w23 = f32x2{wgv[2], wgv[3]};
        b01 = f32x2{bgv[0], bgv[1]}; b23 = f32x2{bgv[2], bgv[3]};
    }
    float whh1v[4], b1v[4];
    #pragma unroll
    for (int g = 0; g < 4; ++g) { whh1v[g] = W_hh1[g]; b1v[g] = b_ih1[g] + b_hh1[g]; }

    const float* inrow = input + (size_t)(bbase + w) * T_STEPS;
    Xb[0][w][l] = inrow[l];
    float xnext = 0.0f;
    float c0 = 0.0f;

    __syncthreads();

    int par = 0;
    #pragma unroll 2
    for (int t = 0; t < T_STEPS; ++t) {
        if ((t & 63) == 0 && t + 64 < T_STEPS) xnext = inrow[t + 64 + l];
        const int cp = (t >> 6) & 1;

        // ---- B-fragments: h(t-1) ----
        const unsigned* Hrow = &Hbuf[par][0][n16][0];
        short8 hb0 = *reinterpret_cast<const short8*>(Hrow + 4 * q16);
        short8 hb1 = *reinterpret_cast<const short8*>(Hrow + 16 + 4 * q16);

        // ---- L1 MFMA ----
        f32x4 accv[4];
        #pragma unroll
        for (int g = 0; g < 4; ++g) {
            f32x4 z = {0.0f, 0.0f, 0.0f, 0.0f};
            z = __builtin_amdgcn_mfma_f32_16x16x32_bf16(a1[g][0], hb0, z, 0, 0, 0);
            z = __builtin_amdgcn_mfma_f32_16x16x32_bf16(a1[g][1], hb1, z, 0, 0, 0);
            accv[g] = z;
        }

        // ---- layer-2 for step t-1 (round-robin wave), in the MFMA shadow ----
        if (t > 0 && w == ((t - 1) & 3)) {
            const unsigned* Ch = &Hbuf[par][1][n16][0];
            const unsigned* Cl = &Hbuf[par][2][n16][0];
            short8 ch0 = *reinterpret_cast<const short8*>(Ch + 4 * q16);
            short8 ch1 = *reinterpret_cast<const short8*>(Ch + 16 + 4 * q16);
            short8 cl0 = *reinterpret_cast<const short8*>(Cl + 4 * q16);
            short8 cl1 = *reinterpret_cast<const short8*>(Cl + 16 + 4 * q16);
            float h1p = Lst[nb], c1p = Lst[4 + nb];
            // two depth-3 accumulation chains
            f32x4 zA = {0.0f, 0.0f, 0.0f, 0.0f};
            f32x4 zB = {0.0f, 0.0f, 0.0f, 0.0f};
            zA = __builtin_amdgcn_mfma_f32_16x16x32_bf16(a2h[0], ch0, zA, 0, 0, 0);
            zB = __builtin_amdgcn_mfma_f32_16x16x32_bf16(a2l[1], ch1, zB, 0, 0, 0);
            zA = __builtin_amdgcn_mfma_f32_16x16x32_bf16(a2h[1], ch1, zA, 0, 0, 0);
            zB = __builtin_amdgcn_mfma_f32_16x16x32_bf16(a2h[0], cl0, zB, 0, 0, 0);
            zA = __builtin_amdgcn_mfma_f32_16x16x32_bf16(a2l[0], ch0, zA, 0, 0, 0);
            zB = __builtin_amdgcn_mfma_f32_16x16x32_bf16(a2h[1], cl1, zB, 0, 0, 0);
            f32x4 z = zA + zB;
            float g1i = z[0] + b1v[0] + h1p * whh1v[0];
            float g1f = z[1] + b1v[1] + h1p * whh1v[1];
            float g1g = z[2] + b1v[2] + h1p * whh1v[2];
            float g1o = z[3] + b1v[3] + h1p * whh1v[3];
            float c1n = sigf(g1f) * c1p + sigf(g1i) * tanh_fast(g1g);
            float h1n = sigf(g1o) * tanh_fast(c1n);
            if (l < 4) {
                out[(size_t)(bbase + l) * T_STEPS + (t - 1)] = c1n;
                Lst[l] = h1n;
                Lst[4 + l] = c1n;
            }
        }

        // ---- in-register gate redistribution (bank-masked DPP, 12 inst) ----
        float g4[4];
        #pragma unroll
        for (int g = 0; g < 4; ++g) g4[g] = sel4A(accv[g]);

        // ---- layer-1 activation for cell (nb, u), packed math ----
        float x = Xb[cp][nb][t & 63];
        f32x2 xx = {x, x};
        f32x2 gif = f32x2{g4[0], g4[1]} + (xx * w01 + b01);   // (i, f)
        f32x2 ggo = f32x2{g4[2], g4[3]} + (xx * w23 + b23);   // (g, o)

        f32x2 sif = sigf2(gif);                  // sig(i), sig(f)
        float tg  = tanh_fast(ggo[0]);
        float c0n = sif[1] * c0 + sif[0] * tg;
        c0 = c0n;
        float h0n = sigf(ggo[1]) * tanh_fast(c0n);

        // ---- pack h / c0hi / c0lo pairs via v_cvt_pk_bf16_f32 ----
        float ph = dpp_shl4f(h0n);               // partner unit u+1 (lane l+4)
        float pc = dpp_shl4f(c0n);
        unsigned hword  = cvt_pk_bf16(h0n, ph);  // lo=own, hi=partner
        unsigned chword = cvt_pk_bf16(c0n, pc);
        float hi_own = bf2f(chword & 0xFFFFu);   // own bf16(c0n) as f32
        float lo_own = c0n - hi_own;
        float plo = dpp_shl4f(lo_own);
        unsigned clword = cvt_pk_bf16(lo_own, plo);
        if (!(l & 4)) {                          // r even: owns pair (u, u+1)
            int widx = 8 * w + 2 * q16 + (r >> 1);
            Hbuf[par ^ 1][0][nb][widx] = hword;
            Hbuf[par ^ 1][1][nb][widx] = chword;
            Hbuf[par ^ 1][2][nb][widx] = clword;
        }
        if ((t & 63) == 63 && t + 1 < T_STEPS) Xb[cp ^ 1][w][l] = xnext;

        __syncthreads();
        par ^= 1;
    }

    // ---- epilogue: layer-2 for step 1023 (wave 3) ----
    if (w == 3) {
        const unsigned* Ch = &Hbuf[par][1][n16][0];
        const unsigned* Cl = &Hbuf[par][2][n16][0];
        short8 ch0 = *reinterpret_cast<const short8*>(Ch + 4 * q16);
        short8 ch1 = *reinterpret_cast<const short8*>(Ch + 16 + 4 * q16);
        short8 cl0 = *reinterpret_cast<const short8*>(Cl + 4 * q16);
        short8 cl1 = *reinterpret_cast<const short8*>(Cl + 16 + 4 * q16);
        float h1p = Lst[nb], c1p = Lst[4 + nb];
        f32x4 zA = {0.0f, 0.0f, 0.0f, 0.0f};
        f32x4 zB = {0.0f, 0.0f, 0.0f, 0.0f};
        zA = __builtin_amdgcn_mfma_f32_16x16x32_bf16(a2h[0], ch0, zA, 0, 0, 0);
        zB = __builtin_amdgcn_mfma_f32_16x16x32_bf16(a2l[1], ch1, zB, 0, 0, 0);
        zA = __builtin_amdgcn_mfma_f32_16x16x32_bf16(a2h[1], ch1, zA, 0, 0, 0);
        zB = __builtin_amdgcn_mfma_f32_16x16x32_bf16(a2h[0], cl0, zB, 0, 0, 0);
        zA = __builtin_amdgcn_mfma_f32_16x16x32_bf16(a2l[0], ch0, zA, 0, 0, 0);
        zB = __builtin_amdgcn_mfma_f32_16x16x32_bf16(a2h[1], cl1, zB, 0, 0, 0);
        f32x4 z = zA + zB;
        float g1i = z[0] + b1v[0] + h1p * whh1v[0];
        float g1f = z[1] + b1v[1] + h1p * whh1v[1];
        float g1g = z[2] + b1v[2] + h1p * whh1v[2];
        float g1o = z[3] + b1v[3] + h1p * whh1v[3];
        float c1n = sigf(g1f) * c1p + sigf(g1i) * tanh_fast(g1g);
        if (l < 4)
            out[(size_t)(bbase + l) * T_STEPS + (T_STEPS - 1)] = c1n;
    }
}

extern "C" void kernel_launch(void* const* d_in, const int* in_sizes, int n_in,
                              void* d_out, int out_size, void* d_ws, size_t ws_size,
                              hipStream_t stream) {
    const float* input = (const float*)d_in[0];
    const float* W_ih0 = (const float*)d_in[1];
    const float* W_hh0 = (const float*)d_in[2];
    const float* b_ih0 = (const float*)d_in[3];
    const float* b_hh0 = (const float*)d_in[4];
    const float* W_ih1 = (const float*)d_in[5];
    const float* W_hh1 = (const float*)d_in[6];
    const float* b_ih1 = (const float*)d_in[7];
    const float* b_hh1 = (const float*)d_in[8];
    float* out = (float*)d_out;

    dim3 grid(BATCH / BTILE);   // 512 blocks -> 2 blocks/CU, 2 waves/SIMD
    dim3 block(256);
    lstm_v7_kernel<<<grid, block, 0, stream>>>(
        input, W_ih0, W_hh0, b_ih0, b_hh0, W_ih1, W_hh1, b_ih1, b_hh1, out);
}

// Round 8
// 599.107 us; speedup vs baseline: 1.2922x; 1.0117x over previous
//
#include <hip/hip_runtime.h>

#define T_STEPS 1024
#define BATCH 2048
#define BTILE 4
#define HS 36   // LDS row stride in u32 words; 36 % 32 == 4 -> conflict-free b128 reads

typedef short short8 __attribute__((ext_vector_type(8)));
typedef float f32x4 __attribute__((ext_vector_type(4)));
typedef float f32x2 __attribute__((ext_vector_type(2)));

__device__ __forceinline__ float fast_rcp(float x) {
#if __has_builtin(__builtin_amdgcn_rcpf)
    return __builtin_amdgcn_rcpf(x);
#else
    return 1.0f / x;
#endif
}

__device__ __forceinline__ float fast_exp2(float x) {
#if __has_builtin(__builtin_amdgcn_exp2f)
    return __builtin_amdgcn_exp2f(x);
#else
    return exp2f(x);
#endif
}

__device__ __forceinline__ float sigf(float x) {
    return fast_rcp(1.0f + fast_exp2(-1.44269504f * x));
}

// packed 2-lane sigmoid
__device__ __forceinline__ f32x2 sigf2(f32x2 v) {
    f32x2 t = v * (-1.44269504f);
    f32x2 e = {fast_exp2(t[0]), fast_exp2(t[1])};
    e = e + 1.0f;
    return f32x2{fast_rcp(e[0]), fast_rcp(e[1])};
}

__device__ __forceinline__ float tanh_fast(float x) {
    float e = fast_exp2(2.88539008f * x);
    return 1.0f - 2.0f * fast_rcp(e + 1.0f);
}

// float -> bf16 bits (round-to-nearest-even) — setup only
__device__ __forceinline__ unsigned f2bf(float x) {
    unsigned u = __float_as_uint(x);
    unsigned r = u + 0x7FFFu + ((u >> 16) & 1u);
    return r >> 16;
}
__device__ __forceinline__ float bf2f(unsigned b) {
    return __uint_as_float(b << 16);
}

// packed bf16 convert: dst = {hi16=bf16(b), lo16=bf16(a)}, RNE
__device__ __forceinline__ unsigned cvt_pk_bf16(float a, float b) {
    unsigned r;
    asm("v_cvt_pk_bf16_f32 %0, %1, %2" : "=v"(r) : "v"(a), "v"(b));
    return r;
}

// DPP conventions (HW-validated R2-R7): 0x110+N: lane l <- lane l-N (row-16);
// 0x100+N: lane l <- lane l+N. bank_mask: unselected banks keep OLD dst value.
__device__ __forceinline__ float sel4A(f32x4 a) {
    int v = __float_as_int(a[0]);                                        // bank 0 (r=0)
    v = __builtin_amdgcn_update_dpp(v, __float_as_int(a[1]), 0x114, 0xf, 0x2, false);
    v = __builtin_amdgcn_update_dpp(v, __float_as_int(a[2]), 0x118, 0xf, 0x4, false);
    v = __builtin_amdgcn_update_dpp(v, __float_as_int(a[3]), 0x11C, 0xf, 0x8, false);
    return __int_as_float(v);
}
__device__ __forceinline__ float dpp_shl4f(float v) {
    return __int_as_float(__builtin_amdgcn_update_dpp(0, __float_as_int(v), 0x104, 0xf, 0xf, true));
}

// R7 kernel + co-resident-block de-phasing: blocks i and i+256 share a CU
// (round-robin XCD dispatch); a one-time ~320-cycle sleep offsets the second
// block by ~half a step so the two waves/SIMD cover each other's stalls
// instead of stalling in lockstep.
__global__ __launch_bounds__(256, 2)
void lstm_v8_kernel(const float* __restrict__ input,
                    const float* __restrict__ W_ih0,
                    const float* __restrict__ W_hh0,
                    const float* __restrict__ b_ih0,
                    const float* __restrict__ b_hh0,
                    const float* __restrict__ W_ih1,
                    const float* __restrict__ W_hh1,
                    const float* __restrict__ b_ih1,
                    const float* __restrict__ b_hh1,
                    float* __restrict__ out)
{
    const int tid = threadIdx.x;
    const int w   = tid >> 6;
    const int l   = tid & 63;
    const int q16 = l >> 4;
    const int n16 = l & 15;
    const int nb  = l & 3;
    const int r   = (l >> 2) & 3;
    const int u   = 16 * w + 4 * q16 + r;
    const int bbase = blockIdx.x * BTILE;

    __shared__ __align__(16) unsigned Hbuf[2][3][16][HS];   // 13.8 KB
    __shared__ float Xb[2][BTILE][65];
    __shared__ float Lst[8];                                // h1[0..3], c1[4..7]

    for (int i = tid; i < 2 * 3 * 16 * HS; i += 256)
        reinterpret_cast<unsigned*>(Hbuf)[i] = 0u;
    if (tid < 8) Lst[tid] = 0.0f;

    // ---- L1 A-fragments: a1[g][kt] = W_hh0 tile (w+4g, kt) ----
    short8 a1[4][2];
    #pragma unroll
    for (int g = 0; g < 4; ++g) {
        #pragma unroll
        for (int kt = 0; kt < 2; ++kt) {
            const float* p = W_hh0 + (size_t)(16 * (w + 4 * g) + n16) * 64 + kt * 32 + q16 * 8;
            short8 a;
            #pragma unroll
            for (int j = 0; j < 8; ++j) a[j] = (short)f2bf(p[j]);
            a1[g][kt] = a;
        }
    }
    // ---- L2 A-fragments (hi/lo split), rows m>=4 zero ----
    short8 a2h[2], a2l[2];
    #pragma unroll
    for (int kt = 0; kt < 2; ++kt) {
        short8 ah = {0,0,0,0,0,0,0,0}, al = {0,0,0,0,0,0,0,0};
        if (n16 < 4) {
            const float* p = W_ih1 + (size_t)n16 * 64 + kt * 32 + q16 * 8;
            #pragma unroll
            for (int j = 0; j < 8; ++j) {
                unsigned hb = f2bf(p[j]);
                ah[j] = (short)hb;
                al[j] = (short)f2bf(p[j] - bf2f(hb));
            }
        }
        a2h[kt] = ah; a2l[kt] = al;
    }

    // activation constants for cell (nb, u), packed as float2 pairs
    f32x2 w01, w23, b01, b23;
    {
        float wgv[4], bgv[4];
        #pragma unroll
        for (int g = 0; g < 4; ++g) {
            int row = g * 64 + u;
            wgv[g] = W_ih0[row];
            bgv[g] = b_ih0[row] + b_hh0[row];
        }
        w01 = f32x2{wgv[0], wgv[1]}; w23 = f32x2{wgv[2], wgv[3]};
        b01 = f32x2{bgv[0], bgv[1]}; b23 = f32x2{bgv[2], bgv[3]};
    }
    float whh1v[4], b1v[4];
    #pragma unroll
    for (int g = 0; g < 4; ++g) { whh1v[g] = W_hh1[g]; b1v[g] = b_ih1[g] + b_hh1[g]; }

    const float* inrow = input + (size_t)(bbase + w) * T_STEPS;
    Xb[0][w][l] = inrow[l];
    float xnext = 0.0f;
    float c0 = 0.0f;

    __syncthreads();

    // ---- de-phase: second co-resident block sleeps ~half a step (~320 cyc).
    // One-time offset; steps are equal-length so it persists. Perf-only.
    if (blockIdx.x & 256) {
        __builtin_amdgcn_s_sleep(5);
    }

    int par = 0;
    #pragma unroll 2
    for (int t = 0; t < T_STEPS; ++t) {
        if ((t & 63) == 0 && t + 64 < T_STEPS) xnext = inrow[t + 64 + l];
        const int cp = (t >> 6) & 1;

        // ---- B-fragments: h(t-1) ----
        const unsigned* Hrow = &Hbuf[par][0][n16][0];
        short8 hb0 = *reinterpret_cast<const short8*>(Hrow + 4 * q16);
        short8 hb1 = *reinterpret_cast<const short8*>(Hrow + 16 + 4 * q16);

        // ---- L1 MFMA ----
        f32x4 accv[4];
        #pragma unroll
        for (int g = 0; g < 4; ++g) {
            f32x4 z = {0.0f, 0.0f, 0.0f, 0.0f};
            z = __builtin_amdgcn_mfma_f32_16x16x32_bf16(a1[g][0], hb0, z, 0, 0, 0);
            z = __builtin_amdgcn_mfma_f32_16x16x32_bf16(a1[g][1], hb1, z, 0, 0, 0);
            accv[g] = z;
        }

        // ---- layer-2 for step t-1 (round-robin wave), in the MFMA shadow ----
        if (t > 0 && w == ((t - 1) & 3)) {
            const unsigned* Ch = &Hbuf[par][1][n16][0];
            const unsigned* Cl = &Hbuf[par][2][n16][0];
            short8 ch0 = *reinterpret_cast<const short8*>(Ch + 4 * q16);
            short8 ch1 = *reinterpret_cast<const short8*>(Ch + 16 + 4 * q16);
            short8 cl0 = *reinterpret_cast<const short8*>(Cl + 4 * q16);
            short8 cl1 = *reinterpret_cast<const short8*>(Cl + 16 + 4 * q16);
            float h1p = Lst[nb], c1p = Lst[4 + nb];
            f32x4 zA = {0.0f, 0.0f, 0.0f, 0.0f};
            f32x4 zB = {0.0f, 0.0f, 0.0f, 0.0f};
            zA = __builtin_amdgcn_mfma_f32_16x16x32_bf16(a2h[0], ch0, zA, 0, 0, 0);
            zB = __builtin_amdgcn_mfma_f32_16x16x32_bf16(a2l[1], ch1, zB, 0, 0, 0);
            zA = __builtin_amdgcn_mfma_f32_16x16x32_bf16(a2h[1], ch1, zA, 0, 0, 0);
            zB = __builtin_amdgcn_mfma_f32_16x16x32_bf16(a2h[0], cl0, zB, 0, 0, 0);
            zA = __builtin_amdgcn_mfma_f32_16x16x32_bf16(a2l[0], ch0, zA, 0, 0, 0);
            zB = __builtin_amdgcn_mfma_f32_16x16x32_bf16(a2h[1], cl1, zB, 0, 0, 0);
            f32x4 z = zA + zB;
            float g1i = z[0] + b1v[0] + h1p * whh1v[0];
            float g1f = z[1] + b1v[1] + h1p * whh1v[1];
            float g1g = z[2] + b1v[2] + h1p * whh1v[2];
            float g1o = z[3] + b1v[3] + h1p * whh1v[3];
            float c1n = sigf(g1f) * c1p + sigf(g1i) * tanh_fast(g1g);
            float h1n = sigf(g1o) * tanh_fast(c1n);
            if (l < 4) {
                out[(size_t)(bbase + l) * T_STEPS + (t - 1)] = c1n;
                Lst[l] = h1n;
                Lst[4 + l] = c1n;
            }
        }

        // ---- in-register gate redistribution (bank-masked DPP, 12 inst) ----
        float g4[4];
        #pragma unroll
        for (int g = 0; g < 4; ++g) g4[g] = sel4A(accv[g]);

        // ---- layer-1 activation for cell (nb, u), packed math ----
        float x = Xb[cp][nb][t & 63];
        f32x2 xx = {x, x};
        f32x2 gif = f32x2{g4[0], g4[1]} + (xx * w01 + b01);   // (i, f)
        f32x2 ggo = f32x2{g4[2], g4[3]} + (xx * w23 + b23);   // (g, o)

        f32x2 sif = sigf2(gif);                  // sig(i), sig(f)
        float tg  = tanh_fast(ggo[0]);
        float c0n = sif[1] * c0 + sif[0] * tg;
        c0 = c0n;
        float h0n = sigf(ggo[1]) * tanh_fast(c0n);

        // ---- pack h / c0hi / c0lo pairs via v_cvt_pk_bf16_f32 ----
        float ph = dpp_shl4f(h0n);               // partner unit u+1 (lane l+4)
        float pc = dpp_shl4f(c0n);
        unsigned hword  = cvt_pk_bf16(h0n, ph);  // lo=own, hi=partner
        unsigned chword = cvt_pk_bf16(c0n, pc);
        float hi_own = bf2f(chword & 0xFFFFu);   // own bf16(c0n) as f32
        float lo_own = c0n - hi_own;
        float plo = dpp_shl4f(lo_own);
        unsigned clword = cvt_pk_bf16(lo_own, plo);
        if (!(l & 4)) {                          // r even: owns pair (u, u+1)
            int widx = 8 * w + 2 * q16 + (r >> 1);
            Hbuf[par ^ 1][0][nb][widx] = hword;
            Hbuf[par ^ 1][1][nb][widx] = chword;
            Hbuf[par ^ 1][2][nb][widx] = clword;
        }
        if ((t & 63) == 63 && t + 1 < T_STEPS) Xb[cp ^ 1][w][l] = xnext;

        __syncthreads();
        par ^= 1;
    }

    // ---- epilogue: layer-2 for step 1023 (wave 3) ----
    if (w == 3) {
        const unsigned* Ch = &Hbuf[par][1][n16][0];
        const unsigned* Cl = &Hbuf[par][2][n16][0];
        short8 ch0 = *reinterpret_cast<const short8*>(Ch + 4 * q16);
        short8 ch1 = *reinterpret_cast<const short8*>(Ch + 16 + 4 * q16);
        short8 cl0 = *reinterpret_cast<const short8*>(Cl + 4 * q16);
        short8 cl1 = *reinterpret_cast<const short8*>(Cl + 16 + 4 * q16);
        float h1p = Lst[nb], c1p = Lst[4 + nb];
        f32x4 zA = {0.0f, 0.0f, 0.0f, 0.0f};
        f32x4 zB = {0.0f, 0.0f, 0.0f, 0.0f};
        zA = __builtin_amdgcn_mfma_f32_16x16x32_bf16(a2h[0], ch0, zA, 0, 0, 0);
        zB = __builtin_amdgcn_mfma_f32_16x16x32_bf16(a2l[1], ch1, zB, 0, 0, 0);
        zA = __builtin_amdgcn_mfma_f32_16x16x32_bf16(a2h[1], ch1, zA, 0, 0, 0);
        zB = __builtin_amdgcn_mfma_f32_16x16x32_bf16(a2h[0], cl0, zB, 0, 0, 0);
        zA = __builtin_amdgcn_mfma_f32_16x16x32_bf16(a2l[0], ch0, zA, 0, 0, 0);
        zB = __builtin_amdgcn_mfma_f32_16x16x32_bf16(a2h[1], cl1, zB, 0, 0, 0);
        f32x4 z = zA + zB;
        float g1i = z[0] + b1v[0] + h1p * whh1v[0];
        float g1f = z[1] + b1v[1] + h1p * whh1v[1];
        float g1g = z[2] + b1v[2] + h1p * whh1v[2];
        float g1o = z[3] + b1v[3] + h1p * whh1v[3];
        float c1n = sigf(g1f) * c1p + sigf(g1i) * tanh_fast(g1g);
        if (l < 4)
            out[(size_t)(bbase + l) * T_STEPS + (T_STEPS - 1)] = c1n;
    }
}

extern "C" void kernel_launch(void* const* d_in, const int* in_sizes, int n_in,
                              void* d_out, int out_size, void* d_ws, size_t ws_size,
                              hipStream_t stream) {
    const float* input = (const float*)d_in[0];
    const float* W_ih0 = (const float*)d_in[1];
    const float* W_hh0 = (const float*)d_in[2];
    const float* b_ih0 = (const float*)d_in[3];
    const float* b_hh0 = (const float*)d_in[4];
    const float* W_ih1 = (const float*)d_in[5];
    const float* W_hh1 = (const float*)d_in[6];
    const float* b_ih1 = (const float*)d_in[7];
    const float* b_hh1 = (const float*)d_in[8];
    float* out = (float*)d_out;

    dim3 grid(BATCH / BTILE);   // 512 blocks -> 2 blocks/CU, 2 waves/SIMD
    dim3 block(256);
    lstm_v8_kernel<<<grid, block, 0, stream>>>(
        input, W_ih0, W_hh0, b_ih0, b_hh0, W_ih1, W_hh1, b_ih1, b_hh1, out);
}